// Round 7
// baseline (100.204 us; speedup 1.0000x reference)
//
#include <hip/hip_runtime.h>

#define NROWS 2048
#define MLEN  3000
#define LPAD  4096
#define PAD0  548
#define NLVL  8
#define NT    256
#define RPB   2      // rows per block

union F4 { float4 v; float f[4]; };

// LDS-visibility-only barrier (no vmcnt drain): detail->global write-through
// stays in flight across level boundaries.
__device__ inline void lds_barrier() {
    asm volatile("s_waitcnt lgkmcnt(0)\n\ts_barrier" ::: "memory");
}

// R7: 2 rows/block. R3/R5/R6 all plateaued at ~41us with every pipe <35%
// utilized -> latency-bound, single dependency chain per thread per phase.
// Two rows give each thread 2 independent chains (2x ILP/MLP at every LDS
// and global access) and halve per-row barrier count; thin phases carry 2x
// work per barrier. LDS 37.5KB -> 4 blocks/CU (16 waves). Per-row buffers
// private; detail mirrors (lvl1->SB[1088..2112), lvl2->SA[512..1024),
// lvl>=3->CS) use the same verified dead regions as R5.
__global__ __launch_bounds__(NT, 4) void despawn_kernel(
    const float* __restrict__ x,
    const float* __restrict__ scaling,
    const float* __restrict__ scaling_rec,
    float* __restrict__ recon_out,
    float* __restrict__ coef_out)
{
    __shared__ __align__(16) float SA[RPB][2048];   // 16 KB
    __shared__ __align__(16) float SB[RPB][2176];   // 17 KB
    __shared__ __align__(16) float CS[RPB][512];    // 4 KB
    __shared__ float fsca[64];
    __shared__ float fwav[64];

    const int tid = threadIdx.x;
    const int row0 = blockIdx.x * RPB;
    const float* xr[RPB];
    float* crow[RPB];
#pragma unroll
    for (int r = 0; r < RPB; ++r) {
        xr[r] = x + (size_t)(row0 + r) * MLEN;
        crow[r] = coef_out + (size_t)(row0 + r) * LPAD;
    }

    // wav[k] = scaling_rec[lvl][7-k] * (-1)^k   (_make_wavelet)
    if (tid < 64) {
        const int lvl = tid >> 3, k = tid & 7;
        fsca[tid] = scaling[tid];
        fwav[tid] = scaling_rec[lvl * 8 + (7 - k)] * ((k & 1) ? -1.0f : 1.0f);
    }

    // ---------------- analysis level 0 : two halves through SB ----------------
    // out[j] = sum_k x_pad[(2j-k) mod 4096] f[k]; x_pad[i]=xr[clamp(i-548)], i<0 wraps->xhi
    for (int h = 0; h < 2; ++h) {
        const int j0 = 1024 * h;
        // stage naturals [2*j0-8, 2*j0+2048): ev[c] at SB[4+c], od[c] at SB[1088+4+c]
        for (int gi = tid; gi < 514; gi += NT) {
            const int n0 = 2 * j0 - 8 + 4 * gi;
#pragma unroll
            for (int r = 0; r < RPB; ++r) {
                F4 u;
                if (n0 >= PAD0 && n0 + 3 <= PAD0 + MLEN - 1) {
                    u.v = *reinterpret_cast<const float4*>(xr[r] + (n0 - PAD0));
                } else {
#pragma unroll
                    for (int e = 0; e < 4; ++e) {
                        int n = n0 + e;
                        if (n < 0) n += LPAD;                 // circular wrap into hi pad
                        int g = n - PAD0;
                        g = g < 0 ? 0 : (g > MLEN - 1 ? MLEN - 1 : g);
                        u.f[e] = xr[r][g];
                    }
                }
                *reinterpret_cast<float2*>(&SB[r][2 * gi])        = make_float2(u.f[0], u.f[2]);
                *reinterpret_cast<float2*>(&SB[r][1088 + 2 * gi]) = make_float2(u.f[1], u.f[3]);
            }
        }
        lds_barrier();
        {
            float W[8], S[8];
#pragma unroll
            for (int k = 0; k < 8; ++k) { W[k] = fwav[k]; S[k] = fsca[k]; }
            const int t = tid;                 // 256 items/row, 4 outputs each
#pragma unroll
            for (int r = 0; r < RPB; ++r) {
                const float4* ev4 = reinterpret_cast<const float4*>(&SB[r][0]);
                const float4* od4 = reinterpret_cast<const float4*>(&SB[r][1088]);
                F4 Ea, Eb, Oa, Ob;
                Ea.v = ev4[t];     // ev c = 4t-4..4t-1
                Eb.v = ev4[t + 1]; // ev c = 4t..4t+3
                Oa.v = od4[t];
                Ob.v = od4[t + 1];
                float e[8] = {Ea.f[0],Ea.f[1],Ea.f[2],Ea.f[3],Eb.f[0],Eb.f[1],Eb.f[2],Eb.f[3]};
                float o[8] = {Oa.f[0],Oa.f[1],Oa.f[2],Oa.f[3],Ob.f[0],Ob.f[1],Ob.f[2],Ob.f[3]};
                float ds[4], as[4];
#pragma unroll
                for (int u = 0; u < 4; ++u) {
                    float d = 0.f, a = 0.f;
#pragma unroll
                    for (int m = 0; m < 4; ++m) {
                        const float vE = e[4 + u - m];
                        const float vO = o[3 + u - m];
                        d = fmaf(vE, W[2 * m], d);
                        d = fmaf(vO, W[2 * m + 1], d);
                        a = fmaf(vE, S[2 * m], a);
                        a = fmaf(vO, S[2 * m + 1], a);
                    }
                    ds[u] = d; as[u] = a;
                }
                F4 dv; dv.f[0] = ds[0]; dv.f[1] = ds[1]; dv.f[2] = ds[2]; dv.f[3] = ds[3];
                reinterpret_cast<float4*>(crow[r] + j0)[t] = dv.v;   // details0 -> global
                *reinterpret_cast<float2*>(&SA[r][(j0 >> 1) + 2 * t])        = make_float2(as[0], as[2]);
                *reinterpret_cast<float2*>(&SA[r][1024 + (j0 >> 1) + 2 * t]) = make_float2(as[1], as[3]);
            }
        }
        lds_barrier();
    }

    // ---------------- analysis levels 1..7 : LDS ping-pong ----------------
    {
        int curA = 1;            // 1 => cur is SA, 0 => cur is SB
        int H = 1024;
        int coff = 2048;
        for (int lvl = 1; lvl < NLVL; ++lvl) {
            float W[8], S[8];
#pragma unroll
            for (int k = 0; k < 8; ++k) { W[k] = fwav[lvl * 8 + k]; S[k] = fsca[lvl * 8 + k]; }
            const int q = H >> 2;
            const int qm = q - 1;
            for (int t = tid; t < q; t += NT) {
#pragma unroll
                for (int r = 0; r < RPB; ++r) {
                    float* cur = curA ? &SA[r][0] : &SB[r][0];
                    float* alt = curA ? &SB[r][0] : &SA[r][0];
                    float* mir = (lvl == 1) ? &SB[r][1088]
                               : (lvl == 2) ? &SA[r][512]
                                            : &CS[r][coff - 3584];
                    const float4* ev4 = reinterpret_cast<const float4*>(cur);
                    const float4* od4 = reinterpret_cast<const float4*>(cur + H);
                    F4 Ea, Eb, Oa, Ob;
                    Ea.v = ev4[(t - 1) & qm];
                    Eb.v = ev4[t];
                    Oa.v = od4[(t - 1) & qm];
                    Ob.v = od4[t];
                    float e[8] = {Ea.f[0],Ea.f[1],Ea.f[2],Ea.f[3],Eb.f[0],Eb.f[1],Eb.f[2],Eb.f[3]};
                    float o[8] = {Oa.f[0],Oa.f[1],Oa.f[2],Oa.f[3],Ob.f[0],Ob.f[1],Ob.f[2],Ob.f[3]};
                    float ds[4], as[4];
#pragma unroll
                    for (int u = 0; u < 4; ++u) {
                        float d = 0.f, a = 0.f;
#pragma unroll
                        for (int m = 0; m < 4; ++m) {
                            const float vE = e[4 + u - m];
                            const float vO = o[3 + u - m];
                            d = fmaf(vE, W[2 * m], d);
                            d = fmaf(vO, W[2 * m + 1], d);
                            a = fmaf(vE, S[2 * m], a);
                            a = fmaf(vO, S[2 * m + 1], a);
                        }
                        ds[u] = d; as[u] = a;
                    }
                    F4 dv; dv.f[0] = ds[0]; dv.f[1] = ds[1]; dv.f[2] = ds[2]; dv.f[3] = ds[3];
                    reinterpret_cast<float4*>(crow[r] + coff)[t] = dv.v;  // -> global, in flight
                    reinterpret_cast<float4*>(mir)[t] = dv.v;             // LDS mirror
                    *reinterpret_cast<float2*>(alt + 2 * t)            = make_float2(as[0], as[2]);
                    *reinterpret_cast<float2*>(alt + (H >> 1) + 2 * t) = make_float2(as[1], as[3]);
                }
            }
            lds_barrier();
            coff += H;
            curA ^= 1;
            H >>= 1;
        }
    }

    // final approx (split, 16) in SB -> natural order to crow tail + CS tail
    if (tid < 16) {
#pragma unroll
        for (int r = 0; r < RPB; ++r) {
            const float v = SB[r][((tid & 1) ? 8 : 0) + (tid >> 1)];
            crow[r][LPAD - 16 + tid] = v;
            CS[r][496 + tid] = v;
        }
    }
    // FULL sync: drains crow stores before synthesis's global readback of details0.
    __syncthreads();

    // ---------------- synthesis levels 7..1 (all-LDS) ----------------
    // out[n] = sum_{k≡n mod 2} d[((n+p)/2+m)&lm]*wav[k] + a[..]*sca[k], k=p+2m
    {
        int aIsCS = 1;       // a starts at CS[r][496]; then ping-pong SA,SB,SA,...
        int obufA = 1;       // 1 => obuf is SA
        int len = 16;
        for (int lvl = NLVL - 1; lvl >= 1; --lvl) {
            float W[8], S[8];
#pragma unroll
            for (int k = 0; k < 8; ++k) { W[k] = fwav[lvl * 8 + k]; S[k] = fsca[lvl * 8 + k]; }
            const int Mout = len << 1;
            const int doff = LPAD - (LPAD >> lvl);
            const int gq = Mout >> 3;
            const int fm = (len >> 2) - 1;
            for (int g = tid; g < gq; g += NT) {
#pragma unroll
                for (int r = 0; r < RPB; ++r) {
                    const float4* d4 = (lvl >= 3) ? reinterpret_cast<const float4*>(&CS[r][doff - 3584])
                                     : (lvl == 2) ? reinterpret_cast<const float4*>(&SA[r][512])
                                                  : reinterpret_cast<const float4*>(&SB[r][1088]);
                    const float* ap = aIsCS ? &CS[r][496] : (obufA ? &SB[r][0] : &SA[r][0]);
                    const float4* a4 = reinterpret_cast<const float4*>(ap);
                    float* obuf = obufA ? &SA[r][0] : &SB[r][0];
                    F4 Da, Db, Aa, Ab;
                    Da.v = d4[g]; Db.v = d4[(g + 1) & fm];
                    Aa.v = a4[g]; Ab.v = a4[(g + 1) & fm];
                    float dd[8] = {Da.f[0],Da.f[1],Da.f[2],Da.f[3],Db.f[0],Db.f[1],Db.f[2],Db.f[3]};
                    float aa[8] = {Aa.f[0],Aa.f[1],Aa.f[2],Aa.f[3],Ab.f[0],Ab.f[1],Ab.f[2],Ab.f[3]};
                    float out[8];
#pragma unroll
                    for (int u = 0; u < 8; ++u) {
                        const int p = u & 1, c = (u + 1) >> 1;
                        float s = 0.f;
#pragma unroll
                        for (int m = 0; m < 4; ++m) {
                            s = fmaf(dd[c + m], W[p + 2 * m], s);
                            s = fmaf(aa[c + m], S[p + 2 * m], s);
                        }
                        out[u] = s;
                    }
                    F4 o0, o1;
                    o0.f[0] = out[0]; o0.f[1] = out[1]; o0.f[2] = out[2]; o0.f[3] = out[3];
                    o1.f[0] = out[4]; o1.f[1] = out[5]; o1.f[2] = out[6]; o1.f[3] = out[7];
                    float4* ob4 = reinterpret_cast<float4*>(obuf + 8 * g);
                    ob4[0] = o0.v; ob4[1] = o1.v;
                }
            }
            lds_barrier();
            aIsCS = 0;
            obufA ^= 1;     // next level reads what we just wrote
            len = Mout;
        }
        // after 7 levels (lvl 7..1): approx len 2048 sits in SA (obufA toggled 7x from 1
        // -> last write with obufA==1 at lvl1: wrote SA). Verify: lvl7 writes SA, lvl6 SB,
        // lvl5 SA, lvl4 SB, lvl3 SA, lvl2 SB, lvl1 SA. -> a == SA.
    }

    // ---------------- synthesis level 0 : straight to recon ----------------
    {
        float W[8], S[8];
#pragma unroll
        for (int k = 0; k < 8; ++k) { W[k] = fwav[k]; S[k] = fsca[k]; }
        const int fm = (2048 >> 2) - 1;
        for (int g = tid; g < (LPAD >> 3); g += NT) {
            const int n0 = 8 * g;
#pragma unroll
            for (int r = 0; r < RPB; ++r) {
                const float4* d4 = reinterpret_cast<const float4*>(crow[r]);  // details0 (L2)
                const float4* a4 = reinterpret_cast<const float4*>(&SA[r][0]);
                float* const ro = recon_out + (size_t)(row0 + r) * MLEN;
                F4 Da, Db, Aa, Ab;
                Da.v = d4[g]; Db.v = d4[(g + 1) & fm];
                Aa.v = a4[g]; Ab.v = a4[(g + 1) & fm];
                float dd[8] = {Da.f[0],Da.f[1],Da.f[2],Da.f[3],Db.f[0],Db.f[1],Db.f[2],Db.f[3]};
                float aa[8] = {Aa.f[0],Aa.f[1],Aa.f[2],Aa.f[3],Ab.f[0],Ab.f[1],Ab.f[2],Ab.f[3]};
                float out[8];
#pragma unroll
                for (int u = 0; u < 8; ++u) {
                    const int p = u & 1, c = (u + 1) >> 1;
                    float s = 0.f;
#pragma unroll
                    for (int m = 0; m < 4; ++m) {
                        s = fmaf(dd[c + m], W[p + 2 * m], s);
                        s = fmaf(aa[c + m], S[p + 2 * m], s);
                    }
                    out[u] = s;
                }
                if (n0 >= PAD0 && n0 + 8 <= PAD0 + MLEN) {
                    F4 o0, o1;
                    o0.f[0] = out[0]; o0.f[1] = out[1]; o0.f[2] = out[2]; o0.f[3] = out[3];
                    o1.f[0] = out[4]; o1.f[1] = out[5]; o1.f[2] = out[6]; o1.f[3] = out[7];
                    float4* r4 = reinterpret_cast<float4*>(ro + (n0 - PAD0));
                    r4[0] = o0.v; r4[1] = o1.v;
                } else {
#pragma unroll
                    for (int u = 0; u < 8; ++u) {
                        const int n = n0 + u;
                        if (n >= PAD0 && n < PAD0 + MLEN) ro[n - PAD0] = out[u];
                    }
                }
            }
        }
    }
}

extern "C" void kernel_launch(void* const* d_in, const int* in_sizes, int n_in,
                              void* d_out, int out_size, void* d_ws, size_t ws_size,
                              hipStream_t stream) {
    const float* x           = (const float*)d_in[0];
    const float* scaling     = (const float*)d_in[1];
    const float* scaling_rec = (const float*)d_in[2];
    float* recon = (float*)d_out;                       // 2048*3000 floats
    float* coefo = recon + (size_t)NROWS * MLEN;        // 2048*4096 floats
    despawn_kernel<<<dim3(NROWS / RPB), dim3(NT), 0, stream>>>(x, scaling, scaling_rec,
                                                               recon, coefo);
    (void)in_sizes; (void)n_in; (void)out_size; (void)d_ws; (void)ws_size;
}